// Round 1
// baseline (1537.668 us; speedup 1.0000x reference)
//
#include <hip/hip_runtime.h>

// GCN layer: out = (D^-1/2 (A+I) D^-1/2) X W^T + b
// N=100000 nodes, E=1600000 edges, D=64 features.
//
// Strategy:
//   deg[i] = 1 + indegree(i)              (int atomics)
//   dis[i] = rsqrt(deg[i])
//   tmp[i,:] = x[i,:] * dis[i]^2          (self-loop term; tmp ALIASES d_out)
//   tmp[dst,:] += x[src,:]*dis[src]*dis[dst]   (102.4M float atomics, float4 gathers)
//   out = tmp @ W^T + b                   (in-place tiled fp32 GEMM, K=64)

__global__ void init_deg_kernel(int* __restrict__ deg, int n) {
    int i = blockIdx.x * blockDim.x + threadIdx.x;
    if (i < n) deg[i] = 1;  // self loop
}

__global__ void count_deg_kernel(const int* __restrict__ dst, int* __restrict__ deg, int e) {
    int i = blockIdx.x * blockDim.x + threadIdx.x;
    if (i < e) atomicAdd(&deg[dst[i]], 1);
}

// One thread per (node, quad-of-4-features). Computes dis and the self-loop init.
__global__ void scale_init_kernel(const float* __restrict__ x, const int* __restrict__ deg,
                                  float* __restrict__ dis, float* tmp, int n) {
    int gid = blockIdx.x * blockDim.x + threadIdx.x;
    if (gid >= n * 16) return;
    int node = gid >> 4;
    float di = rsqrtf((float)deg[node]);
    if ((gid & 15) == 0) dis[node] = di;
    float s = di * di;
    float4 v = ((const float4*)x)[gid];
    float4 o;
    o.x = v.x * s; o.y = v.y * s; o.z = v.z * s; o.w = v.w * s;
    ((float4*)tmp)[gid] = o;
}

// One thread per (edge, quad). 16 lanes cooperate on one edge's 64 features.
__global__ void edge_scatter_kernel(const float* __restrict__ x, const int* __restrict__ ei,
                                    const float* __restrict__ dis, float* tmp, int e) {
    int gid = blockIdx.x * blockDim.x + threadIdx.x;
    if (gid >= e * 16) return;
    int edge = gid >> 4;
    int q = gid & 15;
    int s = ei[edge];       // src
    int t = ei[e + edge];   // dst
    float ns = dis[s] * dis[t];
    float4 v = ((const float4*)x)[s * 16 + q];
    float* o = tmp + (size_t)t * 64 + q * 4;
    atomicAdd(o + 0, v.x * ns);
    atomicAdd(o + 1, v.y * ns);
    atomicAdd(o + 2, v.z * ns);
    atomicAdd(o + 3, v.w * ns);
}

// In-place GEMM: out[m, o] = b[o] + sum_k A[m, k] * W[o, k].
// A and out are the SAME buffer (d_out): each block reads exactly the 64 rows
// it overwrites, staged fully into LDS before __syncthreads, so in-place is safe.
// NOTE: no __restrict__ on A/out — they alias.
__global__ __launch_bounds__(256) void gemm_kernel(const float* A,
                                                   const float* __restrict__ W,
                                                   const float* __restrict__ b,
                                                   float* out, int n) {
    __shared__ float At[64 * 68];  // k-major, stride 68 (16B-aligned rows, conflict-free b128)
    __shared__ float Wt[64 * 64];  // Wt[k*64+o] = W[o*64+k]
    int t = threadIdx.x;
    int m0 = blockIdx.x * 64;

#pragma unroll
    for (int j = 0; j < 16; ++j) {
        int idx = t + j * 256;
        int o = idx >> 6, k = idx & 63;
        Wt[k * 64 + o] = W[idx];
    }
#pragma unroll
    for (int j = 0; j < 16; ++j) {
        int idx = t + j * 256;
        int m = idx >> 6, k = idx & 63;
        int gm = m0 + m;
        At[k * 68 + m] = (gm < n) ? A[(size_t)gm * 64 + k] : 0.f;
    }
    __syncthreads();

    int tx = t & 15, ty = t >> 4;  // tx: output quad (o = tx*4..+3), ty: node quad
    float acc[4][4];
#pragma unroll
    for (int i = 0; i < 4; ++i)
#pragma unroll
        for (int j = 0; j < 4; ++j) acc[i][j] = 0.f;

#pragma unroll 8
    for (int k = 0; k < 64; ++k) {
        float4 a = *(const float4*)&At[k * 68 + ty * 4];
        float4 w = *(const float4*)&Wt[k * 64 + tx * 4];
        float av[4] = {a.x, a.y, a.z, a.w};
        float wv[4] = {w.x, w.y, w.z, w.w};
#pragma unroll
        for (int i = 0; i < 4; ++i)
#pragma unroll
            for (int j = 0; j < 4; ++j) acc[i][j] += av[i] * wv[j];
    }

    float4 bb = ((const float4*)b)[tx];
    float bv[4] = {bb.x, bb.y, bb.z, bb.w};
#pragma unroll
    for (int i = 0; i < 4; ++i) {
        int gm = m0 + ty * 4 + i;
        if (gm < n) {
            float4 o;
            o.x = acc[i][0] + bv[0];
            o.y = acc[i][1] + bv[1];
            o.z = acc[i][2] + bv[2];
            o.w = acc[i][3] + bv[3];
            ((float4*)out)[(size_t)gm * 16 + tx] = o;
        }
    }
}

extern "C" void kernel_launch(void* const* d_in, const int* in_sizes, int n_in,
                              void* d_out, int out_size, void* d_ws, size_t ws_size,
                              hipStream_t stream) {
    const float* x  = (const float*)d_in[0];
    const int*   ei = (const int*)d_in[1];   // [2, E]: src row then dst row
    const float* W  = (const float*)d_in[2];
    const float* b  = (const float*)d_in[3];
    float* out = (float*)d_out;

    int n = in_sizes[0] / 64;
    int e = in_sizes[1] / 2;

    // workspace layout: deg (n ints), dis (n floats) — ~800 KB total
    int* deg = (int*)d_ws;
    size_t dis_off = (((size_t)n * sizeof(int)) + 255) & ~(size_t)255;
    float* dis = (float*)((char*)d_ws + dis_off);

    init_deg_kernel<<<(n + 255) / 256, 256, 0, stream>>>(deg, n);
    count_deg_kernel<<<(e + 255) / 256, 256, 0, stream>>>(ei + e, deg, e);
    scale_init_kernel<<<(n * 16 + 255) / 256, 256, 0, stream>>>(x, deg, dis, out, n);
    edge_scatter_kernel<<<((e * 16) + 255) / 256, 256, 0, stream>>>(x, ei, dis, out, e);
    gemm_kernel<<<(n + 63) / 64, 256, 0, stream>>>(out, W, b, out, n);
}

// Round 2
// 393.786 us; speedup vs baseline: 3.9048x; 3.9048x over previous
//
#include <hip/hip_runtime.h>

// GCN layer: out = (D^-1/2 (A+I) D^-1/2) X W^T + b
// N=100000, E=1600000, D=64.
//
// Round 2: pull-mode aggregation via CSR build. Eliminates the 102.4M float
// atomics (round-1 profile: WRITE_SIZE 1.6GB = 1KB/edge write-through, atomic
// pipe bound at 75G atomics/s, VALUBusy 1%, HBM 17%).
//
// Pipeline:
//   cnt[dst]++                      (1.6M int atomics)
//   dis[i] = rsqrt(cnt[i]+1)        (self loop in degree)
//   off = exclusive_scan(cnt)       (2-level scan, off[n]=E)
//   srcs[off[dst]+k] = src          (bucket fill, int atomics on cursors)
//   tmp[i,f] = dis[i] * (x[i,f]*dis[i] + sum_e x[src_e,f]*dis[src_e])
//              (one wave per node, lane=feature, coalesced 256B row reads)
//   out = tmp @ W^T + b             (in-place tiled fp32 GEMM; tmp aliases d_out)

__global__ void zero_int_kernel(int* __restrict__ p, int n) {
    int i = blockIdx.x * blockDim.x + threadIdx.x;
    if (i < n) p[i] = 0;
}

__global__ void hist_kernel(const int* __restrict__ dst, int* __restrict__ cnt, int e) {
    int i = blockIdx.x * blockDim.x + threadIdx.x;
    if (i < e) atomicAdd(&cnt[dst[i]], 1);
}

__global__ void dis_kernel(const int* __restrict__ cnt, float* __restrict__ dis, int n) {
    int i = blockIdx.x * blockDim.x + threadIdx.x;
    if (i < n) dis[i] = rsqrtf((float)(cnt[i] + 1));
}

// --- 2-level exclusive scan over cnt[0..n) -> off[0..n], tile = 1024 ---

__global__ void block_sum_kernel(const int* __restrict__ cnt, int* __restrict__ sums, int n) {
    __shared__ int sm[256];
    int t = threadIdx.x;
    int base = blockIdx.x * 1024 + t * 4;
    int s = 0;
#pragma unroll
    for (int j = 0; j < 4; ++j) {
        int i = base + j;
        if (i < n) s += cnt[i];
    }
    sm[t] = s;
    __syncthreads();
    for (int o = 128; o > 0; o >>= 1) {
        if (t < o) sm[t] += sm[t + o];
        __syncthreads();
    }
    if (t == 0) sums[blockIdx.x] = sm[0];
}

// single block, 1024 threads: exclusive scan of block sums; writes off[n]=total
__global__ void scan_sums_kernel(int* __restrict__ sums, int nb, int* __restrict__ off, int n) {
    __shared__ int sm[1024];
    int t = threadIdx.x;
    int v = (t < nb) ? sums[t] : 0;
    sm[t] = v;
    __syncthreads();
    for (int o = 1; o < 1024; o <<= 1) {
        int add = (t >= o) ? sm[t - o] : 0;
        __syncthreads();
        sm[t] += add;
        __syncthreads();
    }
    if (t < nb) sums[t] = sm[t] - v;  // exclusive
    if (t == nb - 1) off[n] = sm[t];  // grand total = E
}

__global__ void scan_block_kernel(const int* __restrict__ cnt, const int* __restrict__ sums,
                                  int* __restrict__ off, int n) {
    __shared__ int sm[256];
    int t = threadIdx.x;
    int base = blockIdx.x * 1024 + t * 4;
    int c[4];
    int s = 0;
#pragma unroll
    for (int j = 0; j < 4; ++j) {
        int i = base + j;
        c[j] = (i < n) ? cnt[i] : 0;
        s += c[j];
    }
    sm[t] = s;
    __syncthreads();
    for (int o = 1; o < 256; o <<= 1) {
        int add = (t >= o) ? sm[t - o] : 0;
        __syncthreads();
        sm[t] += add;
        __syncthreads();
    }
    int run = sm[t] - s + sums[blockIdx.x];  // exclusive + block offset
#pragma unroll
    for (int j = 0; j < 4; ++j) {
        int i = base + j;
        if (i < n) off[i] = run;
        run += c[j];
    }
}

__global__ void fill_kernel(const int* __restrict__ ei, const int* __restrict__ off,
                            int* __restrict__ cur, int* __restrict__ srcs, int e) {
    int i = blockIdx.x * blockDim.x + threadIdx.x;
    if (i >= e) return;
    int s = ei[i];
    int t = ei[e + i];
    int pos = off[t] + atomicAdd(&cur[t], 1);
    srcs[pos] = s;
}

// One wave per node, lane = feature. Edge list for the node is contiguous (CSR):
// load up to 64 edge ids coalesced, broadcast each (src, dis[src]) via shfl,
// read x[src] row fully coalesced (64 lanes x 4B = 256B), FMA into register.
__global__ __launch_bounds__(256) void gather_kernel(const float* __restrict__ x,
                                                     const int* __restrict__ srcs,
                                                     const int* __restrict__ off,
                                                     const float* __restrict__ dis,
                                                     float* __restrict__ tmp, int n) {
    int wid = (blockIdx.x * blockDim.x + threadIdx.x) >> 6;
    int lane = threadIdx.x & 63;
    if (wid >= n) return;
    int beg = off[wid];
    int end = off[wid + 1];
    float dn = dis[wid];
    float acc = x[(size_t)wid * 64 + lane] * dn;  // self loop: x*dis (scaled by dn again below)
    for (int c = beg; c < end; c += 64) {
        int k = end - c;
        if (k > 64) k = 64;
        int sidx = 0;
        float dv = 0.f;
        if (c + lane < end) {
            sidx = srcs[c + lane];
            dv = dis[sidx];
        }
        for (int j = 0; j < k; ++j) {
            int s = __shfl(sidx, j);
            float w = __shfl(dv, j);
            acc += x[(size_t)s * 64 + lane] * w;
        }
    }
    tmp[(size_t)wid * 64 + lane] = acc * dn;
}

// In-place GEMM: out[m, o] = b[o] + sum_k A[m, k] * W[o, k].
// A and out alias (d_out): each block stages its 64 rows in LDS before writing.
__global__ __launch_bounds__(256) void gemm_kernel(const float* A,
                                                   const float* __restrict__ W,
                                                   const float* __restrict__ b,
                                                   float* out, int n) {
    __shared__ float At[64 * 68];
    __shared__ float Wt[64 * 64];
    int t = threadIdx.x;
    int m0 = blockIdx.x * 64;

#pragma unroll
    for (int j = 0; j < 16; ++j) {
        int idx = t + j * 256;
        int o = idx >> 6, k = idx & 63;
        Wt[k * 64 + o] = W[idx];
    }
#pragma unroll
    for (int j = 0; j < 16; ++j) {
        int idx = t + j * 256;
        int m = idx >> 6, k = idx & 63;
        int gm = m0 + m;
        At[k * 68 + m] = (gm < n) ? A[(size_t)gm * 64 + k] : 0.f;
    }
    __syncthreads();

    int tx = t & 15, ty = t >> 4;
    float acc[4][4];
#pragma unroll
    for (int i = 0; i < 4; ++i)
#pragma unroll
        for (int j = 0; j < 4; ++j) acc[i][j] = 0.f;

#pragma unroll 8
    for (int k = 0; k < 64; ++k) {
        float4 a = *(const float4*)&At[k * 68 + ty * 4];
        float4 w = *(const float4*)&Wt[k * 64 + tx * 4];
        float av[4] = {a.x, a.y, a.z, a.w};
        float wv[4] = {w.x, w.y, w.z, w.w};
#pragma unroll
        for (int i = 0; i < 4; ++i)
#pragma unroll
            for (int j = 0; j < 4; ++j) acc[i][j] += av[i] * wv[j];
    }

    float4 bb = ((const float4*)b)[tx];
    float bv[4] = {bb.x, bb.y, bb.z, bb.w};
#pragma unroll
    for (int i = 0; i < 4; ++i) {
        int gm = m0 + ty * 4 + i;
        if (gm < n) {
            float4 o;
            o.x = acc[i][0] + bv[0];
            o.y = acc[i][1] + bv[1];
            o.z = acc[i][2] + bv[2];
            o.w = acc[i][3] + bv[3];
            ((float4*)out)[(size_t)gm * 16 + tx] = o;
        }
    }
}

extern "C" void kernel_launch(void* const* d_in, const int* in_sizes, int n_in,
                              void* d_out, int out_size, void* d_ws, size_t ws_size,
                              hipStream_t stream) {
    const float* x  = (const float*)d_in[0];
    const int*   ei = (const int*)d_in[1];  // [2, E]: src row then dst row
    const float* W  = (const float*)d_in[2];
    const float* b  = (const float*)d_in[3];
    float* out = (float*)d_out;

    int n = in_sizes[0] / 64;
    int e = in_sizes[1] / 2;
    int nb = (n + 1023) / 1024;  // scan blocks (98 for n=100k; scan_sums supports <=1024)

    // workspace layout (256B aligned): cnt | off | dis | sums | srcs  (~8.1 MB)
    auto align = [](size_t v) { return (v + 255) & ~(size_t)255; };
    char* p = (char*)d_ws;
    int* cnt = (int*)p;                 p += align((size_t)n * 4);
    int* off = (int*)p;                 p += align((size_t)(n + 1) * 4);
    float* dis = (float*)p;             p += align((size_t)n * 4);
    int* sums = (int*)p;                p += align((size_t)nb * 4);
    int* srcs = (int*)p;

    zero_int_kernel<<<(n + 255) / 256, 256, 0, stream>>>(cnt, n);
    hist_kernel<<<(e + 255) / 256, 256, 0, stream>>>(ei + e, cnt, e);
    dis_kernel<<<(n + 255) / 256, 256, 0, stream>>>(cnt, dis, n);
    block_sum_kernel<<<nb, 256, 0, stream>>>(cnt, sums, n);
    scan_sums_kernel<<<1, 1024, 0, stream>>>(sums, nb, off, n);
    scan_block_kernel<<<nb, 256, 0, stream>>>(cnt, sums, off, n);
    zero_int_kernel<<<(n + 255) / 256, 256, 0, stream>>>(cnt, n);  // reuse as cursor
    fill_kernel<<<(e + 255) / 256, 256, 0, stream>>>(ei, off, cnt, srcs, e);
    gather_kernel<<<(n + 3) / 4, 256, 0, stream>>>(x, srcs, off, dis, out, n);
    gemm_kernel<<<(n + 63) / 64, 256, 0, stream>>>(out, W, b, out, n);
}

// Round 3
// 223.005 us; speedup vs baseline: 6.8952x; 1.7658x over previous
//
#include <hip/hip_runtime.h>

// GCN layer: out = (D^-1/2 (A+I) D^-1/2) X W^T + b
// N=100000, E=1600000, D=64.
//
// Round 3: two-level counting sort for the CSR build. Round-2 profile showed
// fill_kernel at 115 us with WRITE_SIZE=107MB for 6.4MB of srcs data (~17x
// write amplification: random 4B scatters -> per-line partial write-backs
// duplicated across non-coherent XCD L2s). Fix: bucket edges (128 nodes per
// bucket) so every written cache line belongs to exactly one block.
//
// Pipeline:
//   A: coarse hist over NBUCK=ceil(n/128) dst-buckets (LDS hist -> global)
//   B: scan 782 bucket counts -> boff, gcur
//   C: binned scatter: block stages 8192 edges in LDS, one global atomicAdd
//      per (block,bucket) claims a contiguous range, writes rec=(src<<7|dlow)
//   D: per-bucket block: LDS hist/scan over 128 nodes -> srcs (sorted), off,
//      dis=rsqrt(deg+1)  (fused; all writes block-exclusive, coalesced)
//   gather: wave per node, lane=feature-quad, 4 edges/iter via float4 rows
//   gemm: in-place tiled fp32 GEMM (tmp aliases d_out)

#define BSHIFT 7
#define BNODES 128  // nodes per bucket

__global__ void zero_int_kernel(int* __restrict__ p, int n) {
    int i = blockIdx.x * blockDim.x + threadIdx.x;
    if (i < n) p[i] = 0;
}

// --- Phase A: coarse histogram over dst >> 7 ---
__global__ __launch_bounds__(256) void coarse_hist_kernel(const int* __restrict__ dst,
                                                          int* __restrict__ gcnt,
                                                          int e, int nbuck) {
    extern __shared__ int lh[];
    for (int i = threadIdx.x; i < nbuck; i += 256) lh[i] = 0;
    __syncthreads();
    int stride = gridDim.x * 256;
    for (int i = blockIdx.x * 256 + threadIdx.x; i < e; i += stride)
        atomicAdd(&lh[dst[i] >> BSHIFT], 1);
    __syncthreads();
    for (int i = threadIdx.x; i < nbuck; i += 256) {
        int c = lh[i];
        if (c) atomicAdd(&gcnt[i], c);
    }
}

// --- Phase B: single-block scan of bucket counts (nbuck <= 1024) ---
__global__ void scan_kernel(const int* __restrict__ gcnt, int nbuck,
                            int* __restrict__ boff, int* __restrict__ gcur,
                            int e, int* __restrict__ off, int n) {
    __shared__ int sm[1024];
    int t = threadIdx.x;
    int v = (t < nbuck) ? gcnt[t] : 0;
    sm[t] = v;
    __syncthreads();
    for (int o = 1; o < 1024; o <<= 1) {
        int add = (t >= o) ? sm[t - o] : 0;
        __syncthreads();
        sm[t] += add;
        __syncthreads();
    }
    if (t < nbuck) {
        int ex = sm[t] - v;
        boff[t] = ex;
        gcur[t] = ex;
    }
    if (t == 0) {
        boff[nbuck] = e;
        off[n] = e;  // CSR sentinel
    }
}

// --- Phase C: binned scatter of packed edge records into bucket regions ---
#define EPB 8192  // edges per block
__global__ __launch_bounds__(256) void binned_scatter_kernel(const int* __restrict__ ei,
                                                             int* __restrict__ gcur,
                                                             unsigned int* __restrict__ grec,
                                                             int e, int nbuck) {
    __shared__ unsigned int lrec[EPB];
    __shared__ unsigned short lbk[EPB];
    extern __shared__ int dyn[];
    int* lh = dyn;            // [nbuck] hist, then cursor
    int* lbase = dyn + nbuck; // [nbuck]
    int t = threadIdx.x;
    for (int i = t; i < nbuck; i += 256) lh[i] = 0;
    __syncthreads();
    int e0 = blockIdx.x * EPB;
    for (int i = t; i < EPB; i += 256) {
        int g = e0 + i;
        if (g >= e) break;
        int s = ei[g];
        int d = ei[e + g];
        int b = d >> BSHIFT;
        lrec[i] = ((unsigned int)s << BSHIFT) | (unsigned int)(d & (BNODES - 1));
        lbk[i] = (unsigned short)b;
        atomicAdd(&lh[b], 1);
    }
    __syncthreads();
    for (int b = t; b < nbuck; b += 256) {
        int c = lh[b];
        lbase[b] = c ? atomicAdd(&gcur[b], c) : 0;
        lh[b] = 0;  // reuse as local cursor
    }
    __syncthreads();
    for (int i = t; i < EPB; i += 256) {
        int g = e0 + i;
        if (g >= e) break;
        int b = lbk[i];
        int pos = lbase[b] + atomicAdd(&lh[b], 1);
        grec[pos] = lrec[i];
    }
}

// --- Phase D: per-bucket fine sort -> CSR srcs + off + dis ---
__global__ __launch_bounds__(256) void bucket_csr_kernel(const unsigned int* __restrict__ grec,
                                                         const int* __restrict__ boff,
                                                         int* __restrict__ srcs,
                                                         int* __restrict__ off,
                                                         float* __restrict__ dis, int n) {
    __shared__ int lh[BNODES];   // hist, then cursor
    __shared__ int ls[BNODES];   // scan
    int t = threadIdx.x;
    int b = blockIdx.x;
    int beg = boff[b];
    int end = boff[b + 1];
    int node0 = b << BSHIFT;
    if (t < BNODES) lh[t] = 0;
    __syncthreads();
    for (int i = beg + t; i < end; i += 256)
        atomicAdd(&lh[grec[i] & (BNODES - 1)], 1);
    __syncthreads();
    int c = (t < BNODES) ? lh[t] : 0;
    if (t < BNODES) ls[t] = c;
    __syncthreads();
    for (int o = 1; o < BNODES; o <<= 1) {
        int add = (t < BNODES && t >= o) ? ls[t - o] : 0;
        __syncthreads();
        if (t < BNODES) ls[t] += add;
        __syncthreads();
    }
    int ex = (t < BNODES) ? (ls[t] - c) : 0;  // exclusive
    if (t < BNODES) {
        int node = node0 + t;
        if (node < n) {
            off[node] = beg + ex;
            dis[node] = rsqrtf((float)(c + 1));  // +1 self loop
        }
        ls[t] = ex;   // keep exclusive offsets
        lh[t] = 0;    // cursor
    }
    __syncthreads();
    for (int i = beg + t; i < end; i += 256) {
        unsigned int r = grec[i];
        int nd = r & (BNODES - 1);
        int pos = beg + ls[nd] + atomicAdd(&lh[nd], 1);
        srcs[pos] = (int)(r >> BSHIFT);
    }
}

// --- Gather: one wave per node, lane = feature-quad, 4 edges per iteration ---
__global__ __launch_bounds__(256) void gather_kernel(const float4* __restrict__ xv,
                                                     const int* __restrict__ srcs,
                                                     const int* __restrict__ off,
                                                     const float* __restrict__ dis,
                                                     float4* __restrict__ tmpv, int n) {
    int wid = (blockIdx.x * 256 + threadIdx.x) >> 6;
    int lane = threadIdx.x & 63;
    if (wid >= n) return;
    int grp = lane >> 4;   // which of 4 concurrent edges
    int fq = lane & 15;    // feature quad
    int beg = off[wid];
    int end = off[wid + 1];
    float dn = dis[wid];
    float4 acc = {0.f, 0.f, 0.f, 0.f};
    if (grp == 0) {  // self loop term: x[wid]*dn (scaled by dn again at the end)
        float4 v = xv[(size_t)wid * 16 + fq];
        acc.x = v.x * dn; acc.y = v.y * dn; acc.z = v.z * dn; acc.w = v.w * dn;
    }
    for (int c = beg; c < end; c += 64) {
        int k = end - c;
        if (k > 64) k = 64;
        int sidx = 0;
        float dv = 0.f;
        if (lane < k) {
            sidx = srcs[c + lane];
            dv = dis[sidx];
        }
        for (int j = 0; j < k; j += 4) {
            int jj = j + grp;                 // jj <= 63 always (k<=64, j%4==0)
            int s = __shfl(sidx, jj);
            float w = __shfl(dv, jj);         // lanes >= k carry w=0 -> harmless
            float4 v = xv[(size_t)s * 16 + fq];
            acc.x += v.x * w; acc.y += v.y * w; acc.z += v.z * w; acc.w += v.w * w;
        }
    }
    // butterfly-reduce the 4 edge-groups (xor 16, 32)
    for (int m = 16; m < 64; m <<= 1) {
        acc.x += __shfl_xor(acc.x, m);
        acc.y += __shfl_xor(acc.y, m);
        acc.z += __shfl_xor(acc.z, m);
        acc.w += __shfl_xor(acc.w, m);
    }
    if (lane < 16) {
        float4 o;
        o.x = acc.x * dn; o.y = acc.y * dn; o.z = acc.z * dn; o.w = acc.w * dn;
        tmpv[(size_t)wid * 16 + lane] = o;
    }
}

// --- In-place GEMM: out[m,o] = b[o] + sum_k A[m,k]*W[o,k]; A aliases out ---
__global__ __launch_bounds__(256) void gemm_kernel(const float* A,
                                                   const float* __restrict__ W,
                                                   const float* __restrict__ b,
                                                   float* out, int n) {
    __shared__ float At[64 * 68];
    __shared__ float Wt[64 * 64];
    int t = threadIdx.x;
    int m0 = blockIdx.x * 64;

#pragma unroll
    for (int j = 0; j < 16; ++j) {
        int idx = t + j * 256;
        int o = idx >> 6, k = idx & 63;
        Wt[k * 64 + o] = W[idx];
    }
#pragma unroll
    for (int j = 0; j < 16; ++j) {
        int idx = t + j * 256;
        int m = idx >> 6, k = idx & 63;
        int gm = m0 + m;
        At[k * 68 + m] = (gm < n) ? A[(size_t)gm * 64 + k] : 0.f;
    }
    __syncthreads();

    int tx = t & 15, ty = t >> 4;
    float acc[4][4];
#pragma unroll
    for (int i = 0; i < 4; ++i)
#pragma unroll
        for (int j = 0; j < 4; ++j) acc[i][j] = 0.f;

#pragma unroll 8
    for (int k = 0; k < 64; ++k) {
        float4 a = *(const float4*)&At[k * 68 + ty * 4];
        float4 w = *(const float4*)&Wt[k * 64 + tx * 4];
        float av[4] = {a.x, a.y, a.z, a.w};
        float wv[4] = {w.x, w.y, w.z, w.w};
#pragma unroll
        for (int i = 0; i < 4; ++i)
#pragma unroll
            for (int j = 0; j < 4; ++j) acc[i][j] += av[i] * wv[j];
    }

    float4 bb = ((const float4*)b)[tx];
    float bv[4] = {bb.x, bb.y, bb.z, bb.w};
#pragma unroll
    for (int i = 0; i < 4; ++i) {
        int gm = m0 + ty * 4 + i;
        if (gm < n) {
            float4 o;
            o.x = acc[i][0] + bv[0];
            o.y = acc[i][1] + bv[1];
            o.z = acc[i][2] + bv[2];
            o.w = acc[i][3] + bv[3];
            ((float4*)out)[(size_t)gm * 16 + tx] = o;
        }
    }
}

extern "C" void kernel_launch(void* const* d_in, const int* in_sizes, int n_in,
                              void* d_out, int out_size, void* d_ws, size_t ws_size,
                              hipStream_t stream) {
    const float* x  = (const float*)d_in[0];
    const int*   ei = (const int*)d_in[1];  // [2,E]: src row then dst row
    const float* W  = (const float*)d_in[2];
    const float* b  = (const float*)d_in[3];
    float* out = (float*)d_out;

    int n = in_sizes[0] / 64;
    int e = in_sizes[1] / 2;
    int nbuck = (n + BNODES - 1) / BNODES;  // 782 for n=100k (<=1024 for scan)

    // workspace (256B aligned): gcnt | boff | gcur | off | dis | grec | srcs  (~13.6MB)
    auto align = [](size_t v) { return (v + 255) & ~(size_t)255; };
    char* p = (char*)d_ws;
    int* gcnt = (int*)p;          p += align((size_t)nbuck * 4);
    int* boff = (int*)p;          p += align((size_t)(nbuck + 1) * 4);
    int* gcur = (int*)p;          p += align((size_t)nbuck * 4);
    int* off  = (int*)p;          p += align((size_t)(n + 1) * 4);
    float* dis = (float*)p;       p += align((size_t)n * 4);
    unsigned int* grec = (unsigned int*)p;  p += align((size_t)e * 4);
    int* srcs = (int*)p;

    size_t lds_hist = (size_t)nbuck * 4;
    size_t lds_scatter = (size_t)nbuck * 8;

    zero_int_kernel<<<(nbuck + 255) / 256, 256, 0, stream>>>(gcnt, nbuck);
    coarse_hist_kernel<<<256, 256, lds_hist, stream>>>(ei + e, gcnt, e, nbuck);
    scan_kernel<<<1, 1024, 0, stream>>>(gcnt, nbuck, boff, gcur, e, off, n);
    binned_scatter_kernel<<<(e + EPB - 1) / EPB, 256, lds_scatter, stream>>>(ei, gcur, grec, e, nbuck);
    bucket_csr_kernel<<<nbuck, 256, 0, stream>>>(grec, boff, srcs, off, dis, n);
    gather_kernel<<<(n + 3) / 4, 256, 0, stream>>>((const float4*)x, srcs, off, dis,
                                                   (float4*)out, n);
    gemm_kernel<<<(n + 63) / 64, 256, 0, stream>>>(out, W, b, out, n);
}